// Round 1
// baseline (124.422 us; speedup 1.0000x reference)
//
#include <hip/hip_runtime.h>
#include <math.h>

// FeedForwardQuantum, analytically collapsed:
//   q_in[n][j]  = dot(x[n], W1[j]) + b1[j]                    (j = 0..7 only!)
//   zpre[j]     = cos(th_j)*cos(q_in_j) - sin(th_j)*sin(q_in_j)*sin(phi_j)
//   q_out[i]    = prod_{j<=i} zpre[j]   (i>=1);   q_out[0] = prod_{j=1..7} zpre[j]
//   out[n][k]   = sum_j q_out[n][j] * W2[k][j] + b2[k]
// (CNOT ring = basis permutation; product state => <Z_i> factorizes over the
//  XOR subsets; omega never affects <Z>.)

constexpr int EMBED = 1024;
constexpr int NQ    = 8;
constexpr int ROWS  = 8;    // rows per block
constexpr int BLOCK = 256;

__global__ __launch_bounds__(BLOCK, 4)
void ffq_fused(const float* __restrict__ x,    // [rows][1024]
               const float* __restrict__ W1,   // [4096][1024], rows 0..7 used
               const float* __restrict__ b1,   // [4096], 0..7 used
               const float* __restrict__ qp,   // [8][3] (phi, theta, omega)
               const float* __restrict__ W2,   // [1024][8]
               const float* __restrict__ b2,   // [1024]
               float* __restrict__ out,        // [rows][1024]
               int total_rows)
{
    const int t    = threadIdx.x;
    const int lane = t & 63;
    const int wv   = t >> 6;
    const int c4   = t << 2;          // this thread's 4 columns (0..1023)

    __shared__ float wsum[4][NQ];
    __shared__ float qoutS[NQ];

    // ---- per-block-resident register fragments (amortized over ROWS rows) ----
    float4 w1r[NQ];                   // W1[j][c4..c4+3]
#pragma unroll
    for (int j = 0; j < NQ; ++j)
        w1r[j] = *reinterpret_cast<const float4*>(W1 + j * EMBED + c4);

    float4 w2lo[4], w2hi[4];          // W2[c4+i][0..7]
#pragma unroll
    for (int i = 0; i < 4; ++i) {
        w2lo[i] = *reinterpret_cast<const float4*>(W2 + (c4 + i) * NQ);
        w2hi[i] = *reinterpret_cast<const float4*>(W2 + (c4 + i) * NQ + 4);
    }
    const float4 b2r = *reinterpret_cast<const float4*>(b2 + c4);

    // qubit constants (uniform; only thread 0 consumes them)
    float cth[NQ], ssps[NQ], b1r[NQ];
#pragma unroll
    for (int j = 0; j < NQ; ++j) {
        const float phi = qp[j * 3 + 0];
        const float th  = qp[j * 3 + 1];
        cth[j]  = cosf(th);
        ssps[j] = sinf(th) * sinf(phi);
        b1r[j]  = b1[j];
    }

    const long base = (long)blockIdx.x * ROWS;
    float4 xv = make_float4(0.f, 0.f, 0.f, 0.f);
    if (base < total_rows)
        xv = *reinterpret_cast<const float4*>(x + base * EMBED + c4);

    for (int r = 0; r < ROWS; ++r) {
        const long row = base + r;
        if (row >= total_rows) break;           // block-uniform

        // prefetch next row's x before the barrier chain
        float4 xn = make_float4(0.f, 0.f, 0.f, 0.f);
        if (r + 1 < ROWS && row + 1 < total_rows)
            xn = *reinterpret_cast<const float4*>(x + (row + 1) * EMBED + c4);

        // ---- 8 partial dot products over this thread's 4 columns ----
        float p[NQ];
#pragma unroll
        for (int j = 0; j < NQ; ++j)
            p[j] = xv.x * w1r[j].x + xv.y * w1r[j].y +
                   xv.z * w1r[j].z + xv.w * w1r[j].w;

        // ---- wave (64-lane) reduction ----
#pragma unroll
        for (int off = 32; off > 0; off >>= 1) {
#pragma unroll
            for (int j = 0; j < NQ; ++j)
                p[j] += __shfl_down(p[j], off, 64);
        }
        if (lane == 0) {
#pragma unroll
            for (int j = 0; j < NQ; ++j) wsum[wv][j] = p[j];
        }
        __syncthreads();

        // ---- quantum closed form (thread 0) ----
        if (t == 0) {
            float zp[NQ];
#pragma unroll
            for (int j = 0; j < NQ; ++j) {
                const float qin = wsum[0][j] + wsum[1][j] + wsum[2][j] +
                                  wsum[3][j] + b1r[j];
                float sq, cq;
                sincosf(qin, &sq, &cq);
                zp[j] = cth[j] * cq - ssps[j] * sq;
            }
            float pr = zp[0];
#pragma unroll
            for (int j = 1; j < NQ; ++j) { pr *= zp[j]; qoutS[j] = pr; }
            pr = zp[1];
#pragma unroll
            for (int j = 2; j < NQ; ++j) pr *= zp[j];
            qoutS[0] = pr;
        }
        __syncthreads();

        // ---- output GEMV slice: out[row][c4..c4+3] ----
        const float q0 = qoutS[0], q1 = qoutS[1], q2 = qoutS[2], q3 = qoutS[3];
        const float q4 = qoutS[4], q5 = qoutS[5], q6 = qoutS[6], q7 = qoutS[7];

        float4 o;
        o.x = b2r.x + q0 * w2lo[0].x + q1 * w2lo[0].y + q2 * w2lo[0].z + q3 * w2lo[0].w
                    + q4 * w2hi[0].x + q5 * w2hi[0].y + q6 * w2hi[0].z + q7 * w2hi[0].w;
        o.y = b2r.y + q0 * w2lo[1].x + q1 * w2lo[1].y + q2 * w2lo[1].z + q3 * w2lo[1].w
                    + q4 * w2hi[1].x + q5 * w2hi[1].y + q6 * w2hi[1].z + q7 * w2hi[1].w;
        o.z = b2r.z + q0 * w2lo[2].x + q1 * w2lo[2].y + q2 * w2lo[2].z + q3 * w2lo[2].w
                    + q4 * w2hi[2].x + q5 * w2hi[2].y + q6 * w2hi[2].z + q7 * w2hi[2].w;
        o.w = b2r.w + q0 * w2lo[3].x + q1 * w2lo[3].y + q2 * w2lo[3].z + q3 * w2lo[3].w
                    + q4 * w2hi[3].x + q5 * w2hi[3].y + q6 * w2hi[3].z + q7 * w2hi[3].w;

        *reinterpret_cast<float4*>(out + (size_t)row * EMBED + c4) = o;

        xv = xn;
    }
}

extern "C" void kernel_launch(void* const* d_in, const int* in_sizes, int n_in,
                              void* d_out, int out_size, void* d_ws, size_t ws_size,
                              hipStream_t stream) {
    const float* x  = (const float*)d_in[0];
    const float* W1 = (const float*)d_in[1];
    const float* b1 = (const float*)d_in[2];
    const float* qp = (const float*)d_in[3];
    const float* W2 = (const float*)d_in[4];
    const float* b2 = (const float*)d_in[5];
    float* out = (float*)d_out;

    const int rows = in_sizes[0] / EMBED;           // 4*2048 = 8192
    const int grid = (rows + ROWS - 1) / ROWS;      // 1024

    hipLaunchKernelGGL(ffq_fused, dim3(grid), dim3(BLOCK), 0, stream,
                       x, W1, b1, qp, W2, b2, out, rows);
}

// Round 2
// 108.100 us; speedup vs baseline: 1.1510x; 1.1510x over previous
//
#include <hip/hip_runtime.h>
#include <math.h>

// FeedForwardQuantum collapsed closed-form (verified round 1):
//   q_j  = dot(x[n], W1[j]) + b1[j]                      (j = 0..7)
//   zp_j = cos(th_j)cos(q_j) - sin(th_j)sin(phi_j)sin(q_j) = R_j cos(q_j + d_j)
//   qout[i] = prod_{j<=i} zp_j (i>=1);  qout[0] = prod_{j=1..7} zp_j
//   out[n][k] = b2[k] + sum_j qout[j] * W2[k][j]
//
// Structure: wave-per-row, zero barriers in row loop. W1 in LDS (32 KB,
// staged once/block), W2+b2 in per-lane registers (amortized over 4 rows).
// Reduce = 10-shfl transpose-reduce; trig = 1 v_cos per qubit in lane j.

constexpr int EMBED = 1024;
constexpr int NQ    = 8;
constexpr int BLOCK = 256;          // 4 waves
constexpr int WAVES = BLOCK / 64;
constexpr int RPW   = 4;            // rows per wave
constexpr float INV2PI = 0.15915494309189535f;

__global__ __launch_bounds__(BLOCK, 2)
void ffq(const float* __restrict__ x,    // [rows][1024]
         const float* __restrict__ W1,   // [4096][1024] (rows 0..7 used)
         const float* __restrict__ b1,   // [4096]
         const float* __restrict__ qp,   // [8][3]
         const float* __restrict__ W2,   // [1024][8]
         const float* __restrict__ b2,   // [1024]
         float* __restrict__ out,        // [rows][1024]
         int total_rows)
{
    const int t    = threadIdx.x;
    const int lane = t & 63;
    const int wv   = t >> 6;

    __shared__ float lds_w1[NQ * EMBED];          // 32 KB

    // ---- stage W1 rows 0..7 into LDS (coalesced float4) ----
    {
        const float4* src = reinterpret_cast<const float4*>(W1);
        float4* dst = reinterpret_cast<float4*>(lds_w1);
#pragma unroll
        for (int k = 0; k < (NQ * EMBED / 4) / BLOCK; ++k)   // 8 iters
            dst[k * BLOCK + t] = src[k * BLOCK + t];
    }

    // ---- per-lane qubit constants (qubit j = lane&7), once per kernel ----
    const int j = lane & 7;
    float Rj, qoffj;
    {
        const float phi = qp[j * 3 + 0];
        const float th  = qp[j * 3 + 1];
        const float cth  = cosf(th);
        const float ssps = sinf(th) * sinf(phi);
        Rj    = sqrtf(cth * cth + ssps * ssps);
        qoffj = (b1[j] + atan2f(ssps, cth)) * INV2PI;
    }

    // ---- W2 / b2 register fragments for this lane's 16 output cols ----
    // chunk i covers cols c = i*256 + lane*4 .. +3
    float4 w2a[4][4], w2b[4][4];   // w2a[i][q] = W2[c+q][0..3], w2b = [4..7]
    float4 b2f[4];
#pragma unroll
    for (int i = 0; i < 4; ++i) {
        const int c = i * 256 + lane * 4;
#pragma unroll
        for (int q = 0; q < 4; ++q) {
            w2a[i][q] = *reinterpret_cast<const float4*>(W2 + (c + q) * NQ);
            w2b[i][q] = *reinterpret_cast<const float4*>(W2 + (c + q) * NQ + 4);
        }
        b2f[i] = *reinterpret_cast<const float4*>(b2 + c);
    }

    __syncthreads();   // LDS staging complete (only barrier in the kernel)

    const int  gw = blockIdx.x * WAVES + wv;
    const long r0 = (long)gw * RPW;

    float4 xv[4];
    if (r0 < total_rows) {
#pragma unroll
        for (int i = 0; i < 4; ++i)
            xv[i] = *reinterpret_cast<const float4*>(
                x + (size_t)r0 * EMBED + i * 256 + lane * 4);
    }

    for (int rr = 0; rr < RPW; ++rr) {
        const long row = r0 + rr;
        if (row >= total_rows) break;       // wave-uniform

        // prefetch next row's x
        float4 xn[4];
        const bool more = (rr + 1 < RPW) && (row + 1 < total_rows);
        if (more) {
#pragma unroll
            for (int i = 0; i < 4; ++i)
                xn[i] = *reinterpret_cast<const float4*>(
                    x + (size_t)(row + 1) * EMBED + i * 256 + lane * 4);
        }

        // ---- partial dots: 8 qubits over this lane's 16 cols ----
        float p[NQ];
#pragma unroll
        for (int jj = 0; jj < NQ; ++jj) p[jj] = 0.f;
#pragma unroll
        for (int i = 0; i < 4; ++i) {
#pragma unroll
            for (int jj = 0; jj < NQ; ++jj) {
                const float4 w = *reinterpret_cast<const float4*>(
                    lds_w1 + jj * EMBED + i * 256 + lane * 4);
                p[jj] += xv[i].x * w.x + xv[i].y * w.y +
                         xv[i].z * w.z + xv[i].w * w.w;
            }
        }

        // ---- transpose-reduce (masks 4,2,1): lane ends with qubit lane&7 ----
        float q4[4], q2[2], tsum;
        {
            const bool up = (lane & 4);
#pragma unroll
            for (int k = 0; k < 4; ++k) {
                const float snd = up ? p[k]     : p[k + 4];
                const float kp  = up ? p[k + 4] : p[k];
                q4[k] = kp + __shfl_xor(snd, 4, 64);
            }
        }
        {
            const bool up = (lane & 2);
#pragma unroll
            for (int k = 0; k < 2; ++k) {
                const float snd = up ? q4[k]     : q4[k + 2];
                const float kp  = up ? q4[k + 2] : q4[k];
                q2[k] = kp + __shfl_xor(snd, 2, 64);
            }
        }
        {
            const bool up = (lane & 1);
            const float snd = up ? q2[0] : q2[1];
            const float kp  = up ? q2[1] : q2[0];
            tsum = kp + __shfl_xor(snd, 1, 64);
        }
        tsum += __shfl_xor(tsum, 8, 64);
        tsum += __shfl_xor(tsum, 16, 64);
        tsum += __shfl_xor(tsum, 32, 64);

        // ---- trig: zp for this lane's qubit (1 v_cos) ----
        const float arg = tsum * INV2PI + qoffj;        // revolutions
        const float zz  = Rj * __builtin_amdgcn_cosf(arg);

        // ---- ordered all-gather of zp[0..7] to every lane (7 shfl) ----
        float z0_, z1_, z2_, z3_, z4_, z5_, z6_, z7_;
        {
            const float o  = __shfl_xor(zz, 1, 64);
            const float a0 = (lane & 1) ? o  : zz;
            const float a1 = (lane & 1) ? zz : o;
            const float rA = __shfl_xor(a0, 2, 64);
            const float rB = __shfl_xor(a1, 2, 64);
            const float c0 = (lane & 2) ? rA : a0;
            const float c1 = (lane & 2) ? rB : a1;
            const float c2 = (lane & 2) ? a0 : rA;
            const float c3 = (lane & 2) ? a1 : rB;
            const float d0 = __shfl_xor(c0, 4, 64);
            const float d1 = __shfl_xor(c1, 4, 64);
            const float d2 = __shfl_xor(c2, 4, 64);
            const float d3 = __shfl_xor(c3, 4, 64);
            z0_ = (lane & 4) ? d0 : c0;
            z1_ = (lane & 4) ? d1 : c1;
            z2_ = (lane & 4) ? d2 : c2;
            z3_ = (lane & 4) ? d3 : c3;
            z4_ = (lane & 4) ? c0 : d0;
            z5_ = (lane & 4) ? c1 : d1;
            z6_ = (lane & 4) ? c2 : d2;
            z7_ = (lane & 4) ? c3 : d3;
        }

        // ---- prefix products ----
        float qo0, qo1, qo2, qo3, qo4, qo5, qo6, qo7;
        qo1 = z0_ * z1_;
        qo2 = qo1 * z2_;
        qo3 = qo2 * z3_;
        qo4 = qo3 * z4_;
        qo5 = qo4 * z5_;
        qo6 = qo5 * z6_;
        qo7 = qo6 * z7_;
        qo0 = z1_ * z2_ * z3_ * z4_ * z5_ * z6_ * z7_;

        // ---- output GEMV from register W2 fragments ----
        float* outp = out + (size_t)row * EMBED;
#pragma unroll
        for (int i = 0; i < 4; ++i) {
            float4 o = b2f[i];
            o.x += qo0 * w2a[i][0].x + qo1 * w2a[i][0].y + qo2 * w2a[i][0].z + qo3 * w2a[i][0].w
                 + qo4 * w2b[i][0].x + qo5 * w2b[i][0].y + qo6 * w2b[i][0].z + qo7 * w2b[i][0].w;
            o.y += qo0 * w2a[i][1].x + qo1 * w2a[i][1].y + qo2 * w2a[i][1].z + qo3 * w2a[i][1].w
                 + qo4 * w2b[i][1].x + qo5 * w2b[i][1].y + qo6 * w2b[i][1].z + qo7 * w2b[i][1].w;
            o.z += qo0 * w2a[i][2].x + qo1 * w2a[i][2].y + qo2 * w2a[i][2].z + qo3 * w2a[i][2].w
                 + qo4 * w2b[i][2].x + qo5 * w2b[i][2].y + qo6 * w2b[i][2].z + qo7 * w2b[i][2].w;
            o.w += qo0 * w2a[i][3].x + qo1 * w2a[i][3].y + qo2 * w2a[i][3].z + qo3 * w2a[i][3].w
                 + qo4 * w2b[i][3].x + qo5 * w2b[i][3].y + qo6 * w2b[i][3].z + qo7 * w2b[i][3].w;
            *reinterpret_cast<float4*>(outp + i * 256 + lane * 4) = o;
        }

#pragma unroll
        for (int i = 0; i < 4; ++i) xv[i] = xn[i];
    }
}

extern "C" void kernel_launch(void* const* d_in, const int* in_sizes, int n_in,
                              void* d_out, int out_size, void* d_ws, size_t ws_size,
                              hipStream_t stream) {
    const float* x  = (const float*)d_in[0];
    const float* W1 = (const float*)d_in[1];
    const float* b1 = (const float*)d_in[2];
    const float* qp = (const float*)d_in[3];
    const float* W2 = (const float*)d_in[4];
    const float* b2 = (const float*)d_in[5];
    float* out = (float*)d_out;

    const int rows = in_sizes[0] / EMBED;                 // 8192
    const int rows_per_block = WAVES * RPW;               // 16
    const int grid = (rows + rows_per_block - 1) / rows_per_block;   // 512

    hipLaunchKernelGGL(ffq, dim3(grid), dim3(BLOCK), 0, stream,
                       x, W1, b1, qp, W2, b2, out, rows);
}